// Round 13
// baseline (435.299 us; speedup 1.0000x reference)
//
#include <hip/hip_runtime.h>
#include <hip/hip_bf16.h>
#include <math.h>

typedef unsigned short u16;
using bf16x8 = __attribute__((ext_vector_type(8))) short;
using f32x4  = __attribute__((ext_vector_type(4))) float;

__device__ inline float b2f(u16 u) {
  unsigned v = ((unsigned)u) << 16;
  return __builtin_bit_cast(float, v);
}
__device__ inline u16 f2b(float f) {
  unsigned u = __builtin_bit_cast(unsigned, f);
  u += 0x7fffu + ((u >> 16) & 1u);
  return (u16)(u >> 16);
}
__device__ inline float gelu_f(float x) {
  float x3 = x * x * x;
  return 0.5f * x * (1.f + tanhf(0.7978845608028654f * (x + 0.044715f * x3)));
}
__device__ inline void gload_lds16(const void* g, void* lds) {
  __builtin_amdgcn_global_load_lds((const __attribute__((address_space(1))) void*)g,
                                   (__attribute__((address_space(3))) void*)lds,
                                   16, 0, 0);
}

#define EPI_SPLIT2 0
#define EPI_F32    1
#define EPI_INIT2H 2
#define EPI_PLAIN  3

// C = A[M,512] @ B[512,N], B given transposed (BT[N][512] bf16).
// Tile BM=128 x BN=64; 8 waves (512 thr) in 4x2, wave tile 32x32 (MR=2,NR=2).
// 3-deep LDS pipeline (72KB, 2 blocks/CU -> 16 waves/CU), counted vmcnt.
template<int EPI>
__global__ __launch_bounds__(512, 4)
void gemm64(const u16* __restrict__ Aptr, int lda,
            const u16* __restrict__ BT,
            void* __restrict__ out0, void* __restrict__ out1, void* __restrict__ out2,
            const u16* __restrict__ fvec, const float* __restrict__ tembv, int t1)
{
  constexpr int MR = 2, NR = 2;
  __shared__ alignas(16) char Ash[3][16384];
  __shared__ alignas(16) char Bsh[3][8192];
  const int tid = threadIdx.x, lane = tid & 63, wid = tid >> 6;   // wid 0..7
  const int wm = wid >> 1, wn = wid & 1;                           // 4 x 2
  const int bm = blockIdx.x, bn = blockIdx.y;

  const int rIn = lane >> 3;
  const int c16log = (lane & 7) ^ (rIn & 7);

  auto stage = [&](int buf, int kt) {
    #pragma unroll
    for (int i = 0; i < 2; ++i) {            // A: 16 chunks of 8 rows, 2/wave
      int c = wid * 2 + i;
      int row = c * 8 + rIn;
      gload_lds16(Aptr + (size_t)(bm * 128 + row) * lda + kt + c16log * 8,
                  Ash[buf] + c * 1024);
    }
    {                                        // B: 8 chunks, 1/wave
      int c = wid;
      int row = c * 8 + rIn;
      gload_lds16(BT + (size_t)(bn * 64 + row) * 512 + kt + c16log * 8,
                  Bsh[buf] + c * 1024);
    }
  };

  f32x4 acc[MR][NR] = {};
  stage(0, 0);
  stage(1, 64);
  #pragma unroll
  for (int kt = 0; kt < 8; ++kt) {
    const int cb = kt % 3;
    if (kt < 6) {
      stage((kt + 2) % 3, (kt + 2) * 64);    // issue 2 tiles ahead (3/wave each)
      asm volatile("s_waitcnt vmcnt(6)" ::: "memory");   // tiles kt+1,kt+2 in flight
    } else if (kt == 6) {
      asm volatile("s_waitcnt vmcnt(3)" ::: "memory");
    } else {
      asm volatile("s_waitcnt vmcnt(0)" ::: "memory");
    }
    __builtin_amdgcn_s_barrier();
    asm volatile("" ::: "memory");
    #pragma unroll
    for (int kk = 0; kk < 64; kk += 32) {
      bf16x8 af[MR], bfr[NR];
      #pragma unroll
      for (int m = 0; m < MR; ++m) {
        int R = wm * 32 + m * 16 + (lane & 15);
        int c16 = (kk >> 3) + (lane >> 4);
        af[m] = *(const bf16x8*)(Ash[cb] + R * 128 + ((c16 ^ (R & 7)) << 4));
      }
      #pragma unroll
      for (int n = 0; n < NR; ++n) {
        int R = wn * 32 + n * 16 + (lane & 15);
        int c16 = (kk >> 3) + (lane >> 4);
        bfr[n] = *(const bf16x8*)(Bsh[cb] + R * 128 + ((c16 ^ (R & 7)) << 4));
      }
      #pragma unroll
      for (int m = 0; m < MR; ++m)
        #pragma unroll
        for (int n = 0; n < NR; ++n)
          acc[m][n] = __builtin_amdgcn_mfma_f32_16x16x32_bf16(af[m], bfr[n], acc[m][n], 0, 0, 0);
    }
    asm volatile("" ::: "memory");
    __builtin_amdgcn_s_barrier();
    asm volatile("" ::: "memory");
  }

  const int row0 = bm * 128 + wm * 32;
  const int col0 = bn * 64 + wn * 32;
  #pragma unroll
  for (int m = 0; m < MR; ++m) {
    #pragma unroll
    for (int n = 0; n < NR; ++n) {
      #pragma unroll
      for (int i = 0; i < 4; ++i) {
        int row = row0 + m * 16 + (lane >> 4) * 4 + i;
        int col = col0 + n * 16 + (lane & 15);
        float v = acc[m][n][i];
        if constexpr (EPI == EPI_SPLIT2) {
          if (col < 512) {
            ((u16*)out0)[((size_t)row * 16 + t1) * 512 + col] = f2b(v + b2f(fvec[col]));
          } else {
            ((u16*)out1)[((size_t)row * 16 + t1) * 512 + (col - 512)] = f2b(v);
          }
        } else if constexpr (EPI == EPI_INIT2H) {
          if (col < 512) {
            ((u16*)out0)[(size_t)row * 16 * 512 + col] = f2b(v);
          } else {
            ((u16*)out1)[(size_t)row * 16 * 512 + (col - 512)] = f2b(v);
            ((u16*)out2)[(size_t)row * 512 + (col - 512)] =
                f2b(gelu_f(v + tembv[col - 512]));
          }
        } else if constexpr (EPI == EPI_PLAIN) {
          ((u16*)out0)[(size_t)row * 512 + col] = f2b(v);
        } else { // EPI_F32
          ((float*)out0)[(size_t)row * 512 + col] = v;
        }
      }
    }
  }
}

// Batched small GEMMs for weight precompute — 8-wave structure (R10 lever).
struct BatchJobs {
  const u16* A[5];
  const u16* BT[5];
  u16* O[5];
  int M[5];
};

__global__ __launch_bounds__(512, 4)
void gemm_batch(BatchJobs jb)
{
  constexpr int MR = 2, NR = 2;
  const int z = blockIdx.z;
  if ((int)blockIdx.x * 128 >= jb.M[z]) return;
  __shared__ alignas(16) char Ash[3][16384];
  __shared__ alignas(16) char Bsh[3][8192];
  const u16* __restrict__ A = jb.A[z];
  const u16* __restrict__ BT = jb.BT[z];
  u16* __restrict__ O = jb.O[z];
  const int tid = threadIdx.x, lane = tid & 63, wid = tid >> 6;
  const int wm = wid >> 1, wn = wid & 1;
  const int bm = blockIdx.x, bn = blockIdx.y;
  const int rIn = lane >> 3;
  const int c16log = (lane & 7) ^ (rIn & 7);

  auto stage = [&](int buf, int kt) {
    #pragma unroll
    for (int i = 0; i < 2; ++i) {
      int c = wid * 2 + i, row = c * 8 + rIn;
      gload_lds16(A + (size_t)(bm * 128 + row) * 512 + kt + c16log * 8,
                  Ash[buf] + c * 1024);
    }
    {
      int c = wid, row = c * 8 + rIn;
      gload_lds16(BT + (size_t)(bn * 64 + row) * 512 + kt + c16log * 8,
                  Bsh[buf] + c * 1024);
    }
  };

  f32x4 acc[MR][NR] = {};
  stage(0, 0);
  stage(1, 64);
  #pragma unroll
  for (int kt = 0; kt < 8; ++kt) {
    const int cb = kt % 3;
    if (kt < 6) {
      stage((kt + 2) % 3, (kt + 2) * 64);
      asm volatile("s_waitcnt vmcnt(6)" ::: "memory");
    } else if (kt == 6) {
      asm volatile("s_waitcnt vmcnt(3)" ::: "memory");
    } else {
      asm volatile("s_waitcnt vmcnt(0)" ::: "memory");
    }
    __builtin_amdgcn_s_barrier();
    asm volatile("" ::: "memory");
    #pragma unroll
    for (int kk = 0; kk < 64; kk += 32) {
      bf16x8 af[MR], bfr[NR];
      #pragma unroll
      for (int m = 0; m < MR; ++m) {
        int R = wm * 32 + m * 16 + (lane & 15);
        int c16 = (kk >> 3) + (lane >> 4);
        af[m] = *(const bf16x8*)(Ash[cb] + R * 128 + ((c16 ^ (R & 7)) << 4));
      }
      #pragma unroll
      for (int n = 0; n < NR; ++n) {
        int R = wn * 32 + n * 16 + (lane & 15);
        int c16 = (kk >> 3) + (lane >> 4);
        bfr[n] = *(const bf16x8*)(Bsh[cb] + R * 128 + ((c16 ^ (R & 7)) << 4));
      }
      #pragma unroll
      for (int m = 0; m < MR; ++m)
        #pragma unroll
        for (int n = 0; n < NR; ++n)
          acc[m][n] = __builtin_amdgcn_mfma_f32_16x16x32_bf16(af[m], bfr[n], acc[m][n], 0, 0, 0);
    }
    asm volatile("" ::: "memory");
    __builtin_amdgcn_s_barrier();
    asm volatile("" ::: "memory");
  }

  const int row0 = bm * 128 + wm * 32;
  const int col0 = bn * 64 + wn * 32;
  #pragma unroll
  for (int m = 0; m < MR; ++m)
    #pragma unroll
    for (int n = 0; n < NR; ++n)
      #pragma unroll
      for (int i = 0; i < 4; ++i) {
        int row = row0 + m * 16 + (lane >> 4) * 4 + i;
        int col = col0 + n * 16 + (lane & 15);
        O[(size_t)row * 512 + col] = f2b(acc[m][n][i]);
      }
}

// one wave per batch row; N compile-time slots. Two-phase loads (K batch ->
// softmax -> V batch) to halve peak VGPR; launch_bounds(256,3) => 12 waves/CU.
template<int N>
__global__ __launch_bounds__(256, 3)
void attend_kernel(const u16* __restrict__ qv, const u16* __restrict__ Kc,
                   const u16* __restrict__ VWc, u16* __restrict__ Hout,
                   const float* __restrict__ temb)
{
  const int lane = threadIdx.x & 63;
  const int r = blockIdx.x * 4 + (threadIdx.x >> 6);
  const float scale = 0.04419417382415922f;
  const size_t base = (size_t)r * 512 + lane * 8;

  bf16x8 q8 = *(const bf16x8*)(qv + base);
  bf16x8 k8[N];
  #pragma unroll
  for (int j = 0; j < N; ++j)
    k8[j] = *(const bf16x8*)(Kc + ((size_t)r * 16 + j) * 512 + lane * 8);

  float qf[8];
  #pragma unroll
  for (int j = 0; j < 8; ++j) qf[j] = b2f((u16)q8[j]);
  float s[N];
  float mx = -1e30f;
  #pragma unroll
  for (int t = 0; t < N; ++t) {
    float d = 0.f;
    #pragma unroll
    for (int j = 0; j < 8; ++j) d += qf[j] * b2f((u16)k8[t][j]);
    #pragma unroll
    for (int off = 32; off > 0; off >>= 1) d += __shfl_xor(d, off, 64);
    s[t] = d * scale;
    mx = fmaxf(mx, s[t]);
  }
  float p[N], sum = 0.f;
  #pragma unroll
  for (int t = 0; t < N; ++t) { p[t] = expf(s[t] - mx); sum += p[t]; }
  const float inv = 1.f / sum;

  __builtin_amdgcn_sched_barrier(0);   // keep V phase after K phase (VGPR cap)

  bf16x8 v8[N];
  #pragma unroll
  for (int j = 0; j < N; ++j)
    v8[j] = *(const bf16x8*)(VWc + ((size_t)r * 16 + j) * 512 + lane * 8);

  float a[8] = {};
  #pragma unroll
  for (int t = 0; t < N; ++t) {
    const float pt = p[t] * inv;
    #pragma unroll
    for (int j = 0; j < 8; ++j) a[j] += pt * b2f((u16)v8[t][j]);
  }
  bf16x8 o;
  #pragma unroll
  for (int j = 0; j < 8; ++j) o[j] = (short)f2b(gelu_f(a[j] + temb[lane * 8 + j]));
  *(bf16x8*)(Hout + base) = o;
}

static inline void launch_attend(int n, const u16* q, const u16* Kc, const u16* VWc,
                                 u16* H, const float* tv, hipStream_t stream)
{
  dim3 g(1024), b(256);
  switch (n) {
    case 2:  attend_kernel<2><<<g, b, 0, stream>>>(q, Kc, VWc, H, tv); break;
    case 3:  attend_kernel<3><<<g, b, 0, stream>>>(q, Kc, VWc, H, tv); break;
    case 4:  attend_kernel<4><<<g, b, 0, stream>>>(q, Kc, VWc, H, tv); break;
    case 5:  attend_kernel<5><<<g, b, 0, stream>>>(q, Kc, VWc, H, tv); break;
    case 6:  attend_kernel<6><<<g, b, 0, stream>>>(q, Kc, VWc, H, tv); break;
    case 7:  attend_kernel<7><<<g, b, 0, stream>>>(q, Kc, VWc, H, tv); break;
    case 8:  attend_kernel<8><<<g, b, 0, stream>>>(q, Kc, VWc, H, tv); break;
    case 9:  attend_kernel<9><<<g, b, 0, stream>>>(q, Kc, VWc, H, tv); break;
    case 10: attend_kernel<10><<<g, b, 0, stream>>>(q, Kc, VWc, H, tv); break;
    case 11: attend_kernel<11><<<g, b, 0, stream>>>(q, Kc, VWc, H, tv); break;
    case 12: attend_kernel<12><<<g, b, 0, stream>>>(q, Kc, VWc, H, tv); break;
    case 13: attend_kernel<13><<<g, b, 0, stream>>>(q, Kc, VWc, H, tv); break;
    case 14: attend_kernel<14><<<g, b, 0, stream>>>(q, Kc, VWc, H, tv); break;
    case 15: attend_kernel<15><<<g, b, 0, stream>>>(q, Kc, VWc, H, tv); break;
    default: attend_kernel<16><<<g, b, 0, stream>>>(q, Kc, VWc, H, tv); break;
  }
}

// One merged prep launch: 5 transposes, 3 conversions, Wik zero-pad, biasK.
__global__ __launch_bounds__(256)
void prep_kernel(const float* __restrict__ x,   const float* __restrict__ Wik,
                 const float* __restrict__ Wiv, const float* __restrict__ Wq,
                 const float* __restrict__ Wk,  const float* __restrict__ Wv,
                 const float* __restrict__ W1,  const float* __restrict__ W2,
                 u16* __restrict__ W1T, u16* __restrict__ W2T, u16* __restrict__ WqT,
                 u16* __restrict__ WkT, u16* __restrict__ WvT,
                 u16* __restrict__ W2b, u16* __restrict__ Wivb, u16* __restrict__ xb,
                 u16* __restrict__ Wikpadb, u16* __restrict__ biasKpad)
{
  const int bid = blockIdx.x, tid = threadIdx.x;
  if (bid < 1280) {                       // transpose-convert f32[512][512]->bf16 T
    __shared__ float tile[32][33];
    const int mat = bid >> 8, local = bid & 255;
    const float* in = (mat == 0) ? W1 : (mat == 1) ? W2 : (mat == 2) ? Wq
                    : (mat == 3) ? Wk : Wv;
    u16* out = (mat == 0) ? W1T : (mat == 1) ? W2T : (mat == 2) ? WqT
             : (mat == 3) ? WkT : WvT;
    const int tx = tid & 31, ty = tid >> 5;
    const int c0 = (local & 15) * 32, r0 = (local >> 4) * 32;
    #pragma unroll
    for (int rr = 0; rr < 32; rr += 8)
      tile[ty + rr][tx] = in[(size_t)(r0 + ty + rr) * 512 + c0 + tx];
    __syncthreads();
    #pragma unroll
    for (int rr = 0; rr < 32; rr += 8)
      out[(size_t)(c0 + ty + rr) * 512 + r0 + tx] = f2b(tile[tx][ty + rr]);
  } else if (bid < 3840) {                // f32->bf16 row-major conversions
    const float* in; u16* out; int local;
    if (bid < 1536)      { in = W2;  out = W2b;  local = bid - 1280; }
    else if (bid < 1792) { in = Wiv; out = Wivb; local = bid - 1536; }
    else                 { in = x;   out = xb;   local = bid - 1792; }
    const int i = local * 256 + tid;
    const float4 v = ((const float4*)in)[i];
    ushort4 o;
    o.x = f2b(v.x); o.y = f2b(v.y); o.z = f2b(v.z); o.w = f2b(v.w);
    ((ushort4*)out)[i] = o;
  } else if (bid < 4096) {                // Wik [512][448] -> bf16 [512][512] pad
    const int local = bid - 3840;
    const int e = local * 1024 + tid * 4;
    const int r = e >> 9, c0 = e & 511;
    ushort4 o;
    float v0 = (c0 + 0 < 448) ? Wik[(size_t)r * 448 + c0 + 0] : 0.f;
    float v1 = (c0 + 1 < 448) ? Wik[(size_t)r * 448 + c0 + 1] : 0.f;
    float v2 = (c0 + 2 < 448) ? Wik[(size_t)r * 448 + c0 + 2] : 0.f;
    float v3 = (c0 + 3 < 448) ? Wik[(size_t)r * 448 + c0 + 3] : 0.f;
    o.x = f2b(v0); o.y = f2b(v1); o.z = f2b(v2); o.w = f2b(v3);
    *(ushort4*)(Wikpadb + (size_t)r * 512 + c0) = o;
  } else {                                // biasK padded to 128 rows, bf16
    const int local = bid - 4096;
    const int t = local >> 1;
    const int col = ((local & 1) << 8) + tid;
    float acc = 0.f;
    if (t < 15) {
      #pragma unroll
      for (int r = 0; r < 64; ++r) {
        float tenc = 3.14159265358979323846f * exp2f(-(float)r);
        acc += sinf((float)t * tenc) * Wk[(size_t)(512 + r) * 512 + col];
      }
    }
    biasKpad[(size_t)t * 512 + col] = f2b(acc);
  }
}

extern "C" void kernel_launch(void* const* d_in, const int* in_sizes, int n_in,
                              void* d_out, int out_size, void* d_ws, size_t ws_size,
                              hipStream_t stream)
{
  const float* x    = (const float*)d_in[0];
  const float* Wik  = (const float*)d_in[1];
  const float* Wiv  = (const float*)d_in[2];
  const float* Wq   = (const float*)d_in[3];
  const float* Wk   = (const float*)d_in[4];
  const float* Wv   = (const float*)d_in[5];
  const float* W1   = (const float*)d_in[6];
  const float* W2   = (const float*)d_in[7];
  const float* temb = (const float*)d_in[8];

  char* ws = (char*)d_ws;
  size_t off = 0;
  auto alloc = [&](size_t bytes) {
    char* p = ws + off;
    off += (bytes + 255) & ~(size_t)255;
    return p;
  };
  const size_t SQ = (size_t)512 * 512 * 2;
  u16* W1T     = (u16*)alloc(SQ);
  u16* W2T     = (u16*)alloc(SQ);
  u16* WqT     = (u16*)alloc(SQ);
  u16* WkT     = (u16*)alloc(SQ);
  u16* WvT     = (u16*)alloc(SQ);
  u16* W2b     = (u16*)alloc(SQ);
  u16* Wivb    = (u16*)alloc(SQ);
  u16* Wikpadb = (u16*)alloc(SQ);
  u16* biasKpad= (u16*)alloc((size_t)128 * 512 * 2);
  u16* W2Wq    = (u16*)alloc(SQ);
  u16* W2WkD   = (u16*)alloc(SQ);
  u16* W2Wv    = (u16*)alloc(SQ);
  u16* biasC   = (u16*)alloc((size_t)128 * 512 * 2);
  u16* PT2     = (u16*)alloc((size_t)1024 * 512 * 2);  // [M ; (W2WvW1)^T]
  u16* ITn     = (u16*)alloc((size_t)1024 * 512 * 2);  // [WzT ; (WivW1)^T]
  u16* xb      = (u16*)alloc((size_t)4096 * 512 * 2);
  u16* Kc      = (u16*)alloc((size_t)4096 * 16 * 512 * 2);  // K' cache
  u16* VWc     = (u16*)alloc((size_t)4096 * 16 * 512 * 2);  // V@W1 cache
  u16* Hb      = (u16*)alloc((size_t)4096 * 512 * 2);

  dim3 blk(256), blk8(512);
  prep_kernel<<<dim3(4352), blk, 0, stream>>>(
      x, Wik, Wiv, Wq, Wk, Wv, W1, W2,
      W1T, W2T, WqT, WkT, WvT, W2b, Wivb, xb, Wikpadb, biasKpad);

  // batch1: W2Wq = W2@Wq, W2WkD = W2@WkD, W2Wv = W2@Wv
  BatchJobs b1 = {};
  b1.A[0] = W2b; b1.BT[0] = WqT; b1.O[0] = W2Wq;  b1.M[0] = 512;
  b1.A[1] = W2b; b1.BT[1] = WkT; b1.O[1] = W2WkD; b1.M[1] = 512;
  b1.A[2] = W2b; b1.BT[2] = WvT; b1.O[2] = W2Wv;  b1.M[2] = 512;
  gemm_batch<<<dim3(4, 8, 3), blk8, 0, stream>>>(b1);

  // batch2: M = W2Wq@(W2WkD)^T        -> PT2 rows 0..511
  //         (W2WvW1)^T = W1T@(W2Wv)^T -> PT2 rows 512..1023
  //         WzT = W2Wq@Wikpad^T       -> ITn rows 0..511
  //         (WivW1)^T = W1T@Wiv^T     -> ITn rows 512..1023
  //         biasC = biasKpad@(W2Wq)^T (rows 15..127 zero)
  BatchJobs b2 = {};
  b2.A[0] = W2Wq;     b2.BT[0] = W2WkD;   b2.O[0] = PT2;                       b2.M[0] = 512;
  b2.A[1] = W1T;      b2.BT[1] = W2Wv;    b2.O[1] = PT2 + (size_t)512 * 512;   b2.M[1] = 512;
  b2.A[2] = W2Wq;     b2.BT[2] = Wikpadb; b2.O[2] = ITn;                       b2.M[2] = 512;
  b2.A[3] = W1T;      b2.BT[3] = Wivb;    b2.O[3] = ITn + (size_t)512 * 512;   b2.M[3] = 512;
  b2.A[4] = biasKpad; b2.BT[4] = W2Wq;    b2.O[4] = biasC;                     b2.M[4] = 128;
  gemm_batch<<<dim3(4, 8, 5), blk8, 0, stream>>>(b2);

  // init: K'_0 = x@Wz, VW_0 = x@(WivW1), H_0 = gelu(VW_0 + temb[0])
  gemm64<EPI_INIT2H><<<dim3(32, 16), blk8, 0, stream>>>(
      xb, 512, ITn, Kc, VWc, Hb, nullptr, temb, 0);

  for (int t = 0; t < 15; ++t) {
    // [K'_{t+1}, VW_{t+1}] = H_t @ [M^T ; W2WvW1]  (+biasC[t] on K')
    gemm64<EPI_SPLIT2><<<dim3(32, 16), blk8, 0, stream>>>(
        Hb, 512, PT2, Kc, VWc, nullptr, biasC + (size_t)t * 512, nullptr, t + 1);
    // H_{t+1} = gelu(attend(H_t, K', VW, n=t+2) + temb[t+1 or 16])
    const int ti = (t == 14) ? 16 : t + 1;
    launch_attend(t + 2, Hb, Kc, VWc, Hb, temb + (size_t)ti * 512, stream);
  }
  gemm64<EPI_F32><<<dim3(32, 8), blk8, 0, stream>>>(
      Hb, 512, W2T, d_out, nullptr, nullptr, nullptr, nullptr, 0);
}

// Round 14
// 432.440 us; speedup vs baseline: 1.0066x; 1.0066x over previous
//
#include <hip/hip_runtime.h>
#include <hip/hip_bf16.h>
#include <math.h>

typedef unsigned short u16;
using bf16x8 = __attribute__((ext_vector_type(8))) short;
using f32x4  = __attribute__((ext_vector_type(4))) float;

__device__ inline float b2f(u16 u) {
  unsigned v = ((unsigned)u) << 16;
  return __builtin_bit_cast(float, v);
}
__device__ inline u16 f2b(float f) {
  unsigned u = __builtin_bit_cast(unsigned, f);
  u += 0x7fffu + ((u >> 16) & 1u);
  return (u16)(u >> 16);
}
__device__ inline float gelu_f(float x) {
  float x3 = x * x * x;
  return 0.5f * x * (1.f + tanhf(0.7978845608028654f * (x + 0.044715f * x3)));
}
__device__ inline void gload_lds16(const void* g, void* lds) {
  __builtin_amdgcn_global_load_lds((const __attribute__((address_space(1))) void*)g,
                                   (__attribute__((address_space(3))) void*)lds,
                                   16, 0, 0);
}

#define EPI_SPLIT2 0
#define EPI_F32    1
#define EPI_INIT2H 2

// C = A[M,512] @ B[512,N], B given transposed (BT[N][512] bf16).
// Tile BM=128 x BN=64; 8 waves (512 thr) in 4x2, wave tile 32x32 (MR=2,NR=2).
// 3-deep LDS pipeline (72KB, 2 blocks/CU -> 16 waves/CU), counted vmcnt.
template<int EPI>
__global__ __launch_bounds__(512, 4)
void gemm64(const u16* __restrict__ Aptr, int lda,
            const u16* __restrict__ BT,
            void* __restrict__ out0, void* __restrict__ out1, void* __restrict__ out2,
            const u16* __restrict__ fvec, const float* __restrict__ tembv, int t1)
{
  constexpr int MR = 2, NR = 2;
  __shared__ alignas(16) char Ash[3][16384];
  __shared__ alignas(16) char Bsh[3][8192];
  const int tid = threadIdx.x, lane = tid & 63, wid = tid >> 6;   // wid 0..7
  const int wm = wid >> 1, wn = wid & 1;                           // 4 x 2
  const int bm = blockIdx.x, bn = blockIdx.y;

  const int rIn = lane >> 3;
  const int c16log = (lane & 7) ^ (rIn & 7);

  auto stage = [&](int buf, int kt) {
    #pragma unroll
    for (int i = 0; i < 2; ++i) {            // A: 16 chunks of 8 rows, 2/wave
      int c = wid * 2 + i;
      int row = c * 8 + rIn;
      gload_lds16(Aptr + (size_t)(bm * 128 + row) * lda + kt + c16log * 8,
                  Ash[buf] + c * 1024);
    }
    {                                        // B: 8 chunks, 1/wave
      int c = wid;
      int row = c * 8 + rIn;
      gload_lds16(BT + (size_t)(bn * 64 + row) * 512 + kt + c16log * 8,
                  Bsh[buf] + c * 1024);
    }
  };

  f32x4 acc[MR][NR] = {};
  stage(0, 0);
  stage(1, 64);
  #pragma unroll
  for (int kt = 0; kt < 8; ++kt) {
    const int cb = kt % 3;
    if (kt < 6) {
      stage((kt + 2) % 3, (kt + 2) * 64);    // issue 2 tiles ahead (3/wave each)
      asm volatile("s_waitcnt vmcnt(6)" ::: "memory");   // tiles kt+1,kt+2 in flight
    } else if (kt == 6) {
      asm volatile("s_waitcnt vmcnt(3)" ::: "memory");
    } else {
      asm volatile("s_waitcnt vmcnt(0)" ::: "memory");
    }
    __builtin_amdgcn_s_barrier();
    asm volatile("" ::: "memory");
    #pragma unroll
    for (int kk = 0; kk < 64; kk += 32) {
      bf16x8 af[MR], bfr[NR];
      #pragma unroll
      for (int m = 0; m < MR; ++m) {
        int R = wm * 32 + m * 16 + (lane & 15);
        int c16 = (kk >> 3) + (lane >> 4);
        af[m] = *(const bf16x8*)(Ash[cb] + R * 128 + ((c16 ^ (R & 7)) << 4));
      }
      #pragma unroll
      for (int n = 0; n < NR; ++n) {
        int R = wn * 32 + n * 16 + (lane & 15);
        int c16 = (kk >> 3) + (lane >> 4);
        bfr[n] = *(const bf16x8*)(Bsh[cb] + R * 128 + ((c16 ^ (R & 7)) << 4));
      }
      #pragma unroll
      for (int m = 0; m < MR; ++m)
        #pragma unroll
        for (int n = 0; n < NR; ++n)
          acc[m][n] = __builtin_amdgcn_mfma_f32_16x16x32_bf16(af[m], bfr[n], acc[m][n], 0, 0, 0);
    }
    asm volatile("" ::: "memory");
    __builtin_amdgcn_s_barrier();
    asm volatile("" ::: "memory");
  }

  const int row0 = bm * 128 + wm * 32;
  const int col0 = bn * 64 + wn * 32;
  #pragma unroll
  for (int m = 0; m < MR; ++m) {
    #pragma unroll
    for (int n = 0; n < NR; ++n) {
      #pragma unroll
      for (int i = 0; i < 4; ++i) {
        int row = row0 + m * 16 + (lane >> 4) * 4 + i;
        int col = col0 + n * 16 + (lane & 15);
        float v = acc[m][n][i];
        if constexpr (EPI == EPI_SPLIT2) {
          if (col < 512) {
            ((u16*)out0)[((size_t)row * 16 + t1) * 512 + col] = f2b(v + b2f(fvec[col]));
          } else {
            ((u16*)out1)[((size_t)row * 16 + t1) * 512 + (col - 512)] = f2b(v);
          }
        } else if constexpr (EPI == EPI_INIT2H) {
          if (col < 512) {
            ((u16*)out0)[(size_t)row * 16 * 512 + col] = f2b(v);
          } else {
            ((u16*)out1)[(size_t)row * 16 * 512 + (col - 512)] = f2b(v);
            ((u16*)out2)[(size_t)row * 512 + (col - 512)] =
                f2b(gelu_f(v + tembv[col - 512]));
          }
        } else { // EPI_F32
          ((float*)out0)[(size_t)row * 512 + col] = v;
        }
      }
    }
  }
}

// Batched small GEMMs for weight precompute — 8-wave structure.
struct BatchJobs {
  const u16* A[5];
  const u16* BT[5];
  u16* O[5];
  int M[5];
};

__global__ __launch_bounds__(512, 4)
void gemm_batch(BatchJobs jb)
{
  constexpr int MR = 2, NR = 2;
  const int z = blockIdx.z;
  if ((int)blockIdx.x * 128 >= jb.M[z]) return;
  __shared__ alignas(16) char Ash[3][16384];
  __shared__ alignas(16) char Bsh[3][8192];
  const u16* __restrict__ A = jb.A[z];
  const u16* __restrict__ BT = jb.BT[z];
  u16* __restrict__ O = jb.O[z];
  const int tid = threadIdx.x, lane = tid & 63, wid = tid >> 6;
  const int wm = wid >> 1, wn = wid & 1;
  const int bm = blockIdx.x, bn = blockIdx.y;
  const int rIn = lane >> 3;
  const int c16log = (lane & 7) ^ (rIn & 7);

  auto stage = [&](int buf, int kt) {
    #pragma unroll
    for (int i = 0; i < 2; ++i) {
      int c = wid * 2 + i, row = c * 8 + rIn;
      gload_lds16(A + (size_t)(bm * 128 + row) * 512 + kt + c16log * 8,
                  Ash[buf] + c * 1024);
    }
    {
      int c = wid, row = c * 8 + rIn;
      gload_lds16(BT + (size_t)(bn * 64 + row) * 512 + kt + c16log * 8,
                  Bsh[buf] + c * 1024);
    }
  };

  f32x4 acc[MR][NR] = {};
  stage(0, 0);
  stage(1, 64);
  #pragma unroll
  for (int kt = 0; kt < 8; ++kt) {
    const int cb = kt % 3;
    if (kt < 6) {
      stage((kt + 2) % 3, (kt + 2) * 64);
      asm volatile("s_waitcnt vmcnt(6)" ::: "memory");
    } else if (kt == 6) {
      asm volatile("s_waitcnt vmcnt(3)" ::: "memory");
    } else {
      asm volatile("s_waitcnt vmcnt(0)" ::: "memory");
    }
    __builtin_amdgcn_s_barrier();
    asm volatile("" ::: "memory");
    #pragma unroll
    for (int kk = 0; kk < 64; kk += 32) {
      bf16x8 af[MR], bfr[NR];
      #pragma unroll
      for (int m = 0; m < MR; ++m) {
        int R = wm * 32 + m * 16 + (lane & 15);
        int c16 = (kk >> 3) + (lane >> 4);
        af[m] = *(const bf16x8*)(Ash[cb] + R * 128 + ((c16 ^ (R & 7)) << 4));
      }
      #pragma unroll
      for (int n = 0; n < NR; ++n) {
        int R = wn * 32 + n * 16 + (lane & 15);
        int c16 = (kk >> 3) + (lane >> 4);
        bfr[n] = *(const bf16x8*)(Bsh[cb] + R * 128 + ((c16 ^ (R & 7)) << 4));
      }
      #pragma unroll
      for (int m = 0; m < MR; ++m)
        #pragma unroll
        for (int n = 0; n < NR; ++n)
          acc[m][n] = __builtin_amdgcn_mfma_f32_16x16x32_bf16(af[m], bfr[n], acc[m][n], 0, 0, 0);
    }
    asm volatile("" ::: "memory");
    __builtin_amdgcn_s_barrier();
    asm volatile("" ::: "memory");
  }

  const int row0 = bm * 128 + wm * 32;
  const int col0 = bn * 64 + wn * 32;
  #pragma unroll
  for (int m = 0; m < MR; ++m)
    #pragma unroll
    for (int n = 0; n < NR; ++n)
      #pragma unroll
      for (int i = 0; i < 4; ++i) {
        int row = row0 + m * 16 + (lane >> 4) * 4 + i;
        int col = col0 + n * 16 + (lane & 15);
        O[(size_t)row * 512 + col] = f2b(acc[m][n][i]);
      }
}

// attend: 512-thread blocks (8 waves), one wave per batch row, 512 blocks.
// N compile-time slots; two-phase loads (K batch -> softmax -> V batch).
template<int N>
__global__ __launch_bounds__(512, 2)
void attend_kernel(const u16* __restrict__ qv, const u16* __restrict__ Kc,
                   const u16* __restrict__ VWc, u16* __restrict__ Hout,
                   const float* __restrict__ temb)
{
  const int lane = threadIdx.x & 63;
  const int r = blockIdx.x * 8 + (threadIdx.x >> 6);
  const float scale = 0.04419417382415922f;
  const size_t base = (size_t)r * 512 + lane * 8;

  bf16x8 q8 = *(const bf16x8*)(qv + base);
  bf16x8 k8[N];
  #pragma unroll
  for (int j = 0; j < N; ++j)
    k8[j] = *(const bf16x8*)(Kc + ((size_t)r * 16 + j) * 512 + lane * 8);

  float qf[8];
  #pragma unroll
  for (int j = 0; j < 8; ++j) qf[j] = b2f((u16)q8[j]);
  float s[N];
  float mx = -1e30f;
  #pragma unroll
  for (int t = 0; t < N; ++t) {
    float d = 0.f;
    #pragma unroll
    for (int j = 0; j < 8; ++j) d += qf[j] * b2f((u16)k8[t][j]);
    #pragma unroll
    for (int off = 32; off > 0; off >>= 1) d += __shfl_xor(d, off, 64);
    s[t] = d * scale;
    mx = fmaxf(mx, s[t]);
  }
  float p[N], sum = 0.f;
  #pragma unroll
  for (int t = 0; t < N; ++t) { p[t] = expf(s[t] - mx); sum += p[t]; }
  const float inv = 1.f / sum;

  __builtin_amdgcn_sched_barrier(0);   // keep V phase after K phase (VGPR cap)

  bf16x8 v8[N];
  #pragma unroll
  for (int j = 0; j < N; ++j)
    v8[j] = *(const bf16x8*)(VWc + ((size_t)r * 16 + j) * 512 + lane * 8);

  float a[8] = {};
  #pragma unroll
  for (int t = 0; t < N; ++t) {
    const float pt = p[t] * inv;
    #pragma unroll
    for (int j = 0; j < 8; ++j) a[j] += pt * b2f((u16)v8[t][j]);
  }
  bf16x8 o;
  #pragma unroll
  for (int j = 0; j < 8; ++j) o[j] = (short)f2b(gelu_f(a[j] + temb[lane * 8 + j]));
  *(bf16x8*)(Hout + base) = o;
}

static inline void launch_attend(int n, const u16* q, const u16* Kc, const u16* VWc,
                                 u16* H, const float* tv, hipStream_t stream)
{
  dim3 g(512), b(512);
  switch (n) {
    case 2:  attend_kernel<2><<<g, b, 0, stream>>>(q, Kc, VWc, H, tv); break;
    case 3:  attend_kernel<3><<<g, b, 0, stream>>>(q, Kc, VWc, H, tv); break;
    case 4:  attend_kernel<4><<<g, b, 0, stream>>>(q, Kc, VWc, H, tv); break;
    case 5:  attend_kernel<5><<<g, b, 0, stream>>>(q, Kc, VWc, H, tv); break;
    case 6:  attend_kernel<6><<<g, b, 0, stream>>>(q, Kc, VWc, H, tv); break;
    case 7:  attend_kernel<7><<<g, b, 0, stream>>>(q, Kc, VWc, H, tv); break;
    case 8:  attend_kernel<8><<<g, b, 0, stream>>>(q, Kc, VWc, H, tv); break;
    case 9:  attend_kernel<9><<<g, b, 0, stream>>>(q, Kc, VWc, H, tv); break;
    case 10: attend_kernel<10><<<g, b, 0, stream>>>(q, Kc, VWc, H, tv); break;
    case 11: attend_kernel<11><<<g, b, 0, stream>>>(q, Kc, VWc, H, tv); break;
    case 12: attend_kernel<12><<<g, b, 0, stream>>>(q, Kc, VWc, H, tv); break;
    case 13: attend_kernel<13><<<g, b, 0, stream>>>(q, Kc, VWc, H, tv); break;
    case 14: attend_kernel<14><<<g, b, 0, stream>>>(q, Kc, VWc, H, tv); break;
    case 15: attend_kernel<15><<<g, b, 0, stream>>>(q, Kc, VWc, H, tv); break;
    default: attend_kernel<16><<<g, b, 0, stream>>>(q, Kc, VWc, H, tv); break;
  }
}

// One merged prep launch: 5 transposes, 3 conversions, Wik zero-pad, biasK.
__global__ __launch_bounds__(256)
void prep_kernel(const float* __restrict__ x,   const float* __restrict__ Wik,
                 const float* __restrict__ Wiv, const float* __restrict__ Wq,
                 const float* __restrict__ Wk,  const float* __restrict__ Wv,
                 const float* __restrict__ W1,  const float* __restrict__ W2,
                 u16* __restrict__ W1T, u16* __restrict__ W2T, u16* __restrict__ WqT,
                 u16* __restrict__ WkT, u16* __restrict__ WvT,
                 u16* __restrict__ W2b, u16* __restrict__ Wivb, u16* __restrict__ xb,
                 u16* __restrict__ Wikpadb, u16* __restrict__ biasKpad)
{
  const int bid = blockIdx.x, tid = threadIdx.x;
  if (bid < 1280) {                       // transpose-convert f32[512][512]->bf16 T
    __shared__ float tile[32][33];
    const int mat = bid >> 8, local = bid & 255;
    const float* in = (mat == 0) ? W1 : (mat == 1) ? W2 : (mat == 2) ? Wq
                    : (mat == 3) ? Wk : Wv;
    u16* out = (mat == 0) ? W1T : (mat == 1) ? W2T : (mat == 2) ? WqT
             : (mat == 3) ? WkT : WvT;
    const int tx = tid & 31, ty = tid >> 5;
    const int c0 = (local & 15) * 32, r0 = (local >> 4) * 32;
    #pragma unroll
    for (int rr = 0; rr < 32; rr += 8)
      tile[ty + rr][tx] = in[(size_t)(r0 + ty + rr) * 512 + c0 + tx];
    __syncthreads();
    #pragma unroll
    for (int rr = 0; rr < 32; rr += 8)
      out[(size_t)(c0 + ty + rr) * 512 + r0 + tx] = f2b(tile[tx][ty + rr]);
  } else if (bid < 3840) {                // f32->bf16 row-major conversions
    const float* in; u16* out; int local;
    if (bid < 1536)      { in = W2;  out = W2b;  local = bid - 1280; }
    else if (bid < 1792) { in = Wiv; out = Wivb; local = bid - 1536; }
    else                 { in = x;   out = xb;   local = bid - 1792; }
    const int i = local * 256 + tid;
    const float4 v = ((const float4*)in)[i];
    ushort4 o;
    o.x = f2b(v.x); o.y = f2b(v.y); o.z = f2b(v.z); o.w = f2b(v.w);
    ((ushort4*)out)[i] = o;
  } else if (bid < 4096) {                // Wik [512][448] -> bf16 [512][512] pad
    const int local = bid - 3840;
    const int e = local * 1024 + tid * 4;
    const int r = e >> 9, c0 = e & 511;
    ushort4 o;
    float v0 = (c0 + 0 < 448) ? Wik[(size_t)r * 448 + c0 + 0] : 0.f;
    float v1 = (c0 + 1 < 448) ? Wik[(size_t)r * 448 + c0 + 1] : 0.f;
    float v2 = (c0 + 2 < 448) ? Wik[(size_t)r * 448 + c0 + 2] : 0.f;
    float v3 = (c0 + 3 < 448) ? Wik[(size_t)r * 448 + c0 + 3] : 0.f;
    o.x = f2b(v0); o.y = f2b(v1); o.z = f2b(v2); o.w = f2b(v3);
    *(ushort4*)(Wikpadb + (size_t)r * 512 + c0) = o;
  } else {                                // biasK padded to 128 rows, bf16
    const int local = bid - 4096;
    const int t = local >> 1;
    const int col = ((local & 1) << 8) + tid;
    float acc = 0.f;
    if (t < 15) {
      #pragma unroll
      for (int r = 0; r < 64; ++r) {
        float tenc = 3.14159265358979323846f * exp2f(-(float)r);
        acc += sinf((float)t * tenc) * Wk[(size_t)(512 + r) * 512 + col];
      }
    }
    biasKpad[(size_t)t * 512 + col] = f2b(acc);
  }
}

extern "C" void kernel_launch(void* const* d_in, const int* in_sizes, int n_in,
                              void* d_out, int out_size, void* d_ws, size_t ws_size,
                              hipStream_t stream)
{
  const float* x    = (const float*)d_in[0];
  const float* Wik  = (const float*)d_in[1];
  const float* Wiv  = (const float*)d_in[2];
  const float* Wq   = (const float*)d_in[3];
  const float* Wk   = (const float*)d_in[4];
  const float* Wv   = (const float*)d_in[5];
  const float* W1   = (const float*)d_in[6];
  const float* W2   = (const float*)d_in[7];
  const float* temb = (const float*)d_in[8];

  char* ws = (char*)d_ws;
  size_t off = 0;
  auto alloc = [&](size_t bytes) {
    char* p = ws + off;
    off += (bytes + 255) & ~(size_t)255;
    return p;
  };
  const size_t SQ = (size_t)512 * 512 * 2;
  u16* W1T     = (u16*)alloc(SQ);
  u16* W2T     = (u16*)alloc(SQ);
  u16* WqT     = (u16*)alloc(SQ);
  u16* WkT     = (u16*)alloc(SQ);
  u16* WvT     = (u16*)alloc(SQ);
  u16* W2b     = (u16*)alloc(SQ);
  u16* Wivb    = (u16*)alloc(SQ);
  u16* Wikpadb = (u16*)alloc(SQ);
  u16* biasKpad= (u16*)alloc((size_t)128 * 512 * 2);
  u16* W2Wq    = (u16*)alloc(SQ);
  u16* W2WkD   = (u16*)alloc(SQ);
  u16* W2Wv    = (u16*)alloc(SQ);
  u16* biasC   = (u16*)alloc((size_t)128 * 512 * 2);
  u16* PT2     = (u16*)alloc((size_t)1024 * 512 * 2);  // [M ; (W2WvW1)^T]
  u16* ITn     = (u16*)alloc((size_t)1024 * 512 * 2);  // [WzT ; (WivW1)^T]
  u16* xb      = (u16*)alloc((size_t)4096 * 512 * 2);
  u16* Kc      = (u16*)alloc((size_t)4096 * 16 * 512 * 2);  // K' cache
  u16* VWc     = (u16*)alloc((size_t)4096 * 16 * 512 * 2);  // V@W1 cache
  u16* Hb      = (u16*)alloc((size_t)4096 * 512 * 2);

  dim3 blk(256), blk8(512);
  prep_kernel<<<dim3(4352), blk, 0, stream>>>(
      x, Wik, Wiv, Wq, Wk, Wv, W1, W2,
      W1T, W2T, WqT, WkT, WvT, W2b, Wivb, xb, Wikpadb, biasKpad);

  // batch1: W2Wq = W2@Wq, W2WkD = W2@WkD, W2Wv = W2@Wv
  BatchJobs b1 = {};
  b1.A[0] = W2b; b1.BT[0] = WqT; b1.O[0] = W2Wq;  b1.M[0] = 512;
  b1.A[1] = W2b; b1.BT[1] = WkT; b1.O[1] = W2WkD; b1.M[1] = 512;
  b1.A[2] = W2b; b1.BT[2] = WvT; b1.O[2] = W2Wv;  b1.M[2] = 512;
  gemm_batch<<<dim3(4, 8, 3), blk8, 0, stream>>>(b1);

  // batch2: M = W2Wq@(W2WkD)^T        -> PT2 rows 0..511
  //         (W2WvW1)^T = W1T@(W2Wv)^T -> PT2 rows 512..1023
  //         WzT = W2Wq@Wikpad^T       -> ITn rows 0..511
  //         (WivW1)^T = W1T@Wiv^T     -> ITn rows 512..1023
  //         biasC = biasKpad@(W2Wq)^T (rows 15..127 zero)
  BatchJobs b2 = {};
  b2.A[0] = W2Wq;     b2.BT[0] = W2WkD;   b2.O[0] = PT2;                       b2.M[0] = 512;
  b2.A[1] = W1T;      b2.BT[1] = W2Wv;    b2.O[1] = PT2 + (size_t)512 * 512;   b2.M[1] = 512;
  b2.A[2] = W2Wq;     b2.BT[2] = Wikpadb; b2.O[2] = ITn;                       b2.M[2] = 512;
  b2.A[3] = W1T;      b2.BT[3] = Wivb;    b2.O[3] = ITn + (size_t)512 * 512;   b2.M[3] = 512;
  b2.A[4] = biasKpad; b2.BT[4] = W2Wq;    b2.O[4] = biasC;                     b2.M[4] = 128;
  gemm_batch<<<dim3(4, 8, 5), blk8, 0, stream>>>(b2);

  // init: K'_0 = x@Wz, VW_0 = x@(WivW1), H_0 = gelu(VW_0 + temb[0])
  gemm64<EPI_INIT2H><<<dim3(32, 16), blk8, 0, stream>>>(
      xb, 512, ITn, Kc, VWc, Hb, nullptr, temb, 0);

  for (int t = 0; t < 15; ++t) {
    // [K'_{t+1}, VW_{t+1}] = H_t @ [M^T ; W2WvW1]  (+biasC[t] on K')
    gemm64<EPI_SPLIT2><<<dim3(32, 16), blk8, 0, stream>>>(
        Hb, 512, PT2, Kc, VWc, nullptr, biasC + (size_t)t * 512, nullptr, t + 1);
    // H_{t+1} = gelu(attend(H_t, K', VW, n=t+2) + temb[t+1 or 16])
    const int ti = (t == 14) ? 16 : t + 1;
    launch_attend(t + 2, Hb, Kc, VWc, Hb, temb + (size_t)ti * 512, stream);
  }
  gemm64<EPI_F32><<<dim3(32, 8), blk8, 0, stream>>>(
      Hb, 512, W2T, d_out, nullptr, nullptr, nullptr, nullptr, 0);
}